// Round 1
// baseline (438.449 us; speedup 1.0000x reference)
//
#include <hip/hip_runtime.h>

// GPTQ int4 linear: out[m,n] = sum_k x[m,k] * (q[n,k]-zero[n,k/64])*scale[n,k/64] + bias[n]
// M=32, K=8192, N=8192, group=64. packed_weight: [N, K/2] int32, one byte (2 nibbles) per elem.
// Design: 4 waves/block, each wave owns TN=4 n-columns over full K; lanes split K.
// x tile staged in LDS, parity-split + transposed (pad 33) -> 2-way bank alias only (free).
// Dequant amortized over all 32 m; weight bytes read exactly once, coalesced.

#define MM 32
#define KK 8192
#define NN 8192
#define KP (KK / 2)   // packed elems per n = 4096
#define NG (KK / 64)  // groups per n = 128
#define BK 256        // k per LDS chunk
#define BP (BK / 2)   // packed per chunk = 128
#define TN 4          // n per wave
#define BN (4 * TN)   // n per block = 16

__global__ __launch_bounds__(256, 2)
void gptq_linear_kernel(const float* __restrict__ x,
                        const int*   __restrict__ pw,
                        const float* __restrict__ scales,
                        const float* __restrict__ zeros,
                        const float* __restrict__ bias,
                        float* __restrict__ out)
{
    // parity-split transposed x tile: xE[r][m] = x[m][kc+2r], xO[r][m] = x[m][kc+2r+1]
    __shared__ float xE[BP][33];
    __shared__ float xO[BP][33];

    const int tid  = threadIdx.x;
    const int lane = tid & 63;
    const int wave = tid >> 6;
    const int n0   = blockIdx.x * BN + wave * TN;

    float acc[TN][MM];
#pragma unroll
    for (int i = 0; i < TN; ++i)
#pragma unroll
        for (int m = 0; m < MM; ++m) acc[i][m] = 0.0f;

    for (int kc = 0; kc < KK; kc += BK) {
        __syncthreads();  // previous chunk fully consumed before overwrite
        // ---- stage x[0:32, kc:kc+256] into LDS (coalesced 1KB rows per wave) ----
#pragma unroll
        for (int t = 0; t < 8; ++t) {
            const int f  = t * 256 + tid;      // float4 index in [0, 2048)
            const int m  = f >> 6;             // row (64 float4 per row)
            const int c4 = f & 63;             // float4 column
            const float4 v = *(const float4*)(x + m * KK + kc + c4 * 4);
            const int r = 2 * c4;
            xE[r][m]     = v.x;   // k local = 4c4
            xO[r][m]     = v.y;   // k local = 4c4+1
            xE[r + 1][m] = v.z;   // k local = 4c4+2
            xO[r + 1][m] = v.w;   // k local = 4c4+3
        }
        __syncthreads();

        const int kc2 = kc >> 1;
#pragma unroll
        for (int s = 0; s < 2; ++s) {
            const int pl = s * 64 + lane;      // local packed index, 0..127
            const int p  = kc2 + pl;           // global packed index
            const int g  = p >> 5;             // quant group (32 packed per group)

            float we[TN], wo[TN];
#pragma unroll
            for (int i = 0; i < TN; ++i) {
                const unsigned b  = (unsigned)pw[(n0 + i) * KP + p] & 0xFFu;
                const float    sc = scales[(n0 + i) * NG + g];
                const float    zp = zeros [(n0 + i) * NG + g];
                we[i] = ((float)(b & 15u) - zp) * sc;   // even k = 2p
                wo[i] = ((float)(b >> 4)  - zp) * sc;   // odd  k = 2p+1
            }
#pragma unroll
            for (int m = 0; m < MM; ++m) {
                const float xe = xE[pl][m];
                const float xo = xO[pl][m];
#pragma unroll
                for (int i = 0; i < TN; ++i) {
                    acc[i][m] = fmaf(xe, we[i], acc[i][m]);
                    acc[i][m] = fmaf(xo, wo[i], acc[i][m]);
                }
            }
        }
    }

    // ---- cross-lane reduce (64-lane butterfly) + bias + store ----
#pragma unroll
    for (int i = 0; i < TN; ++i) {
        const float bv = bias[n0 + i];
#pragma unroll
        for (int m = 0; m < MM; ++m) {
            float v = acc[i][m];
            v += __shfl_xor(v, 1,  64);
            v += __shfl_xor(v, 2,  64);
            v += __shfl_xor(v, 4,  64);
            v += __shfl_xor(v, 8,  64);
            v += __shfl_xor(v, 16, 64);
            v += __shfl_xor(v, 32, 64);
            if (lane == m) out[m * NN + (n0 + i)] = v + bv;
        }
    }
}

extern "C" void kernel_launch(void* const* d_in, const int* in_sizes, int n_in,
                              void* d_out, int out_size, void* d_ws, size_t ws_size,
                              hipStream_t stream) {
    const float* x      = (const float*)d_in[0];
    const int*   pw     = (const int*)  d_in[1];
    const float* scales = (const float*)d_in[2];
    const float* zeros  = (const float*)d_in[3];
    const float* bias   = (const float*)d_in[4];
    float* out = (float*)d_out;

    dim3 grid(NN / BN);   // 512 blocks
    dim3 block(256);
    gptq_linear_kernel<<<grid, block, 0, stream>>>(x, pw, scales, zeros, bias, out);
}

// Round 3
// 220.058 us; speedup vs baseline: 1.9924x; 1.9924x over previous
//
#include <hip/hip_runtime.h>
#include <hip/hip_bf16.h>

// GPTQ int4 linear via bf16 MFMA. M=32, K=8192, N=8192, group=64.
// out = x @ dequant(W)^T + bias, W packed [N, K/2] one byte per int32.
//
// Structure:
//  1) xconv_kernel (only if ws_size >= 512 KB): x fp32 [32,8192] -> bf16 A-frag
//     layout in d_ws. frag f = ((mt*256+ks)*64 + lane),
//     elem j = x[(lane&15)+16mt][ks*32+(lane>>4)*8+j]
//  2) gptq_mfma_kernel<USE_WS>: 512 blocks x 256 thr. Block = 16 n-cols; 4 waves
//     split K (2048 k each, no barriers in main loop). Lane's B-frag = 4
//     consecutive packed int32 (dwordx4 per n-row) dequanted in-register to bf16.
//     4-deep register pipeline on the weight stream. Cross-wave reduce via LDS.
//     USE_WS=false falls back to direct fp32 x loads + in-register cvt (no d_ws).

#define KK 8192
#define NN 8192
#define KP 4096      // int32 per weight row
#define NG 128       // quant groups per row
#define BN 16        // n per block
#define KSW 64       // k-steps (32 k each) per wave; 4 waves * 64 * 32 = 8192
#define NKS 256      // total k-steps

typedef __attribute__((ext_vector_type(8))) short short8;
typedef __attribute__((ext_vector_type(4))) float floatx4;

__device__ __forceinline__ unsigned pack_bf16x2(float lo, float hi) {
    union { __hip_bfloat162 h; unsigned u; } c;
    c.h = __float22bfloat162_rn(make_float2(lo, hi));
    return c.u;
}

__global__ void xconv_kernel(const float* __restrict__ x, ushort* __restrict__ xb)
{
    const int tid = blockIdx.x * 256 + threadIdx.x;   // 0..32767
    const int l   = tid & 63;
    const int ks  = (tid >> 6) & 255;
    const int mt  = tid >> 14;
    const int m   = (l & 15) + 16 * mt;
    const int kb  = ks * 32 + (l >> 4) * 8;
    const float* src = x + (size_t)m * KK + kb;
    const float4 a = *(const float4*)(src);
    const float4 b = *(const float4*)(src + 4);
    *(uint4*)(xb + (size_t)tid * 8) =
        make_uint4(pack_bf16x2(a.x, a.y), pack_bf16x2(a.z, a.w),
                   pack_bf16x2(b.x, b.y), pack_bf16x2(b.z, b.w));
}

template<bool USE_WS>
__global__ __launch_bounds__(256, 2)
void gptq_mfma_kernel(const int*   __restrict__ pw,
                      const float* __restrict__ scales,
                      const float* __restrict__ zeros,
                      const float* __restrict__ bias,
                      const ushort* __restrict__ xb,
                      const float* __restrict__ x,
                      float* __restrict__ out)
{
    __shared__ float s_lds[NG][BN];
    __shared__ float z_lds[NG][BN];
    __shared__ float red[4][2][256];

    const int tid  = threadIdx.x;
    const int lane = tid & 63;
    const int wave = tid >> 6;
    const int n0   = blockIdx.x * BN;

    // stage scales/zeros for this block's 16 rows: [group][n_local]
#pragma unroll
    for (int t = 0; t < 2; ++t) {
        const int e4 = t * 256 + tid;      // float4 index 0..511
        const int r  = e4 >> 5;            // n_local (32 float4 per 128-float row)
        const int gb = (e4 & 31) * 4;
        const float4 s4 = *(const float4*)(scales + (size_t)(n0 + r) * NG + gb);
        const float4 z4 = *(const float4*)(zeros  + (size_t)(n0 + r) * NG + gb);
        s_lds[gb + 0][r] = s4.x; s_lds[gb + 1][r] = s4.y;
        s_lds[gb + 2][r] = s4.z; s_lds[gb + 3][r] = s4.w;
        z_lds[gb + 0][r] = z4.x; z_lds[gb + 1][r] = z4.y;
        z_lds[gb + 2][r] = z4.z; z_lds[gb + 3][r] = z4.w;
    }
    __syncthreads();

    const int nl = lane & 15;   // n within block (B-frag col)
    const int kq = lane >> 4;   // k-quad within k-step
    const int* pwp = pw + (size_t)(n0 + nl) * KP + kq * 4;
    const uint4* xfp = (const uint4*)xb;
    const int ks0 = wave * KSW;

    // direct-load addressing (fallback path)
    const int xm0 = nl;            // m for mt=0; mt=1 adds 16
    const int xkq = kq * 8;

    auto load_xfrag = [&](int mt, int ks) -> uint4 {
        if (USE_WS) {
            return xfp[(size_t)(mt * NKS + ks) * 64 + lane];
        } else {
            const float* src = x + (size_t)(xm0 + 16 * mt) * KK + ks * 32 + xkq;
            const float4 a = *(const float4*)(src);
            const float4 b = *(const float4*)(src + 4);
            return make_uint4(pack_bf16x2(a.x, a.y), pack_bf16x2(a.z, a.w),
                              pack_bf16x2(b.x, b.y), pack_bf16x2(b.z, b.w));
        }
    };

    floatx4 acc0 = {0.f, 0.f, 0.f, 0.f};
    floatx4 acc1 = {0.f, 0.f, 0.f, 0.f};

    int4  pwb[4];
    uint4 x0b[4], x1b[4];

#pragma unroll
    for (int i = 0; i < 3; ++i) {
        const int ks = ks0 + i;
        pwb[i] = *(const int4*)(pwp + ks * 16);
        x0b[i] = load_xfrag(0, ks);
        x1b[i] = load_xfrag(1, ks);
    }

#pragma unroll 4
    for (int i = 0; i < KSW; ++i) {
        const int slot = i & 3;
        if (i + 3 < KSW) {
            const int ks = ks0 + i + 3;
            const int ps = (i + 3) & 3;
            pwb[ps] = *(const int4*)(pwp + ks * 16);
            x0b[ps] = load_xfrag(0, ks);
            x1b[ps] = load_xfrag(1, ks);
        }
        const int ks  = ks0 + i;
        const int g   = ks >> 1;                 // 2 k-steps per quant group
        const float sc = s_lds[g][nl];
        const float zs = -z_lds[g][nl] * sc;     // w = q*sc + zs

        union { uint4 v; short8 s; } bf;
        const int4 p = pwb[slot];
        bf.v.x = pack_bf16x2(fmaf((float)(p.x & 15), sc, zs),
                             fmaf((float)((p.x >> 4) & 15), sc, zs));
        bf.v.y = pack_bf16x2(fmaf((float)(p.y & 15), sc, zs),
                             fmaf((float)((p.y >> 4) & 15), sc, zs));
        bf.v.z = pack_bf16x2(fmaf((float)(p.z & 15), sc, zs),
                             fmaf((float)((p.z >> 4) & 15), sc, zs));
        bf.v.w = pack_bf16x2(fmaf((float)(p.w & 15), sc, zs),
                             fmaf((float)((p.w >> 4) & 15), sc, zs));

        union { uint4 v; short8 s; } a0, a1;
        a0.v = x0b[slot];
        a1.v = x1b[slot];
        acc0 = __builtin_amdgcn_mfma_f32_16x16x32_bf16(a0.s, bf.s, acc0, 0, 0, 0);
        acc1 = __builtin_amdgcn_mfma_f32_16x16x32_bf16(a1.s, bf.s, acc1, 0, 0, 0);
    }

    // cross-wave (K-split) reduction: C/D layout col=lane&15, row=(lane>>4)*4+r
#pragma unroll
    for (int r = 0; r < 4; ++r) {
        const int row = kq * 4 + r;
        red[wave][0][row * 16 + nl] = acc0[r];
        red[wave][1][row * 16 + nl] = acc1[r];
    }
    __syncthreads();

#pragma unroll
    for (int i = 0; i < 2; ++i) {
        const int e   = i * 256 + tid;     // 0..511 output elems of this block
        const int mt  = e >> 8;
        const int idx = e & 255;
        const float s = red[0][mt][idx] + red[1][mt][idx] + red[2][mt][idx] + red[3][mt][idx];
        const int row = idx >> 4, col = idx & 15;
        const int n   = n0 + col;
        out[(size_t)(mt * 16 + row) * NN + n] = s + bias[n];
    }
}

extern "C" void kernel_launch(void* const* d_in, const int* in_sizes, int n_in,
                              void* d_out, int out_size, void* d_ws, size_t ws_size,
                              hipStream_t stream) {
    const float* x      = (const float*)d_in[0];
    const int*   pw     = (const int*)  d_in[1];
    const float* scales = (const float*)d_in[2];
    const float* zeros  = (const float*)d_in[3];
    const float* bias   = (const float*)d_in[4];
    float* out = (float*)d_out;

    const size_t need = (size_t)32768 * 16;   // 512 KB of bf16 A-frags
    if (d_ws != nullptr && ws_size >= need) {
        ushort* xb = (ushort*)d_ws;
        xconv_kernel<<<128, 256, 0, stream>>>(x, xb);
        gptq_mfma_kernel<true><<<512, 256, 0, stream>>>(pw, scales, zeros, bias, xb, x, out);
    } else {
        gptq_mfma_kernel<false><<<512, 256, 0, stream>>>(pw, scales, zeros, bias,
                                                         (const ushort*)nullptr, x, out);
    }
}

// Round 4
// 214.629 us; speedup vs baseline: 2.0428x; 1.0253x over previous
//
#include <hip/hip_runtime.h>
#include <hip/hip_bf16.h>

// GPTQ int4 linear via bf16 MFMA. M=32, K=8192, N=8192, group=64.
// out = x @ dequant(W)^T + bias, W packed [N, K/2] one byte per int32.
//
// R4: K-split x2 across blocks (grid 1024 = 4 blocks/CU, launch_bounds(256,4))
// to fix HBM-latency binding at 2 blocks/CU. Partials combined via atomicAdd;
// prep_kernel pre-fills out with bias (and does x->bf16 A-frag conversion).

#define KK 8192
#define NN 8192
#define KP 4096      // int32 per weight row
#define NG 128       // quant groups per row
#define BN 16        // n per block
#define KSPLIT 2
#define KSW 32       // k-steps (32 k each) per wave: 2 halves * 4 waves * 32 * 32 = 8192
#define NKS 256      // total k-steps

typedef __attribute__((ext_vector_type(8))) short short8;
typedef __attribute__((ext_vector_type(4))) float floatx4;

__device__ __forceinline__ unsigned pack_bf16x2(float lo, float hi) {
    union { __hip_bfloat162 h; unsigned u; } c;
    c.h = __float22bfloat162_rn(make_float2(lo, hi));
    return c.u;
}

// blocks [0, xconv_blocks): x fp32 -> bf16 A-frag layout in xb.
//   frag f = ((mt*256+ks)*64 + lane), elem j = x[(lane&15)+16mt][ks*32+(lane>>4)*8+j]
// blocks [xconv_blocks, xconv_blocks+256): out[m][n] = bias[n] (float4 stores).
__global__ void prep_kernel(const float* __restrict__ x, const float* __restrict__ bias,
                            ushort* __restrict__ xb, float* __restrict__ out,
                            int xconv_blocks)
{
    const int bx = blockIdx.x;
    if (bx < xconv_blocks) {
        const int tid = bx * 256 + threadIdx.x;   // 0..32767
        const int l   = tid & 63;
        const int ks  = (tid >> 6) & 255;
        const int mt  = tid >> 14;
        const int m   = (l & 15) + 16 * mt;
        const int kb  = ks * 32 + (l >> 4) * 8;
        const float* src = x + (size_t)m * KK + kb;
        const float4 a = *(const float4*)(src);
        const float4 b = *(const float4*)(src + 4);
        *(uint4*)(xb + (size_t)tid * 8) =
            make_uint4(pack_bf16x2(a.x, a.y), pack_bf16x2(a.z, a.w),
                       pack_bf16x2(b.x, b.y), pack_bf16x2(b.z, b.w));
    } else {
        const int f4 = (bx - xconv_blocks) * 256 + threadIdx.x;  // 0..65535
        const int n4 = f4 & (NN / 4 - 1);
        const float4 b4 = ((const float4*)bias)[n4];
        ((float4*)out)[f4] = b4;   // f4 == m*(NN/4) + n4
    }
}

template<bool USE_WS>
__global__ __launch_bounds__(256, 4)
void gptq_mfma_kernel(const int*   __restrict__ pw,
                      const float* __restrict__ scales,
                      const float* __restrict__ zeros,
                      const ushort* __restrict__ xb,
                      const float* __restrict__ x,
                      float* __restrict__ out)
{
    __shared__ float s_lds[64][BN + 1];   // this block's K-half: 64 groups x 16 n
    __shared__ float z_lds[64][BN + 1];
    __shared__ float red[4][2][256];

    const int tid  = threadIdx.x;
    const int lane = tid & 63;
    const int wave = tid >> 6;
    const int kh   = blockIdx.x & (KSPLIT - 1);
    const int n0   = (blockIdx.x >> 1) * BN;
    const int g0   = kh * 64;

    // stage this half's scales/zeros: [group_local][n_local]
    {
        const int r  = tid >> 4;          // n_local (16 float4 per 64-float half-row)
        const int gb = (tid & 15) * 4;    // group_local base
        const float4 s4 = *(const float4*)(scales + (size_t)(n0 + r) * NG + g0 + gb);
        const float4 z4 = *(const float4*)(zeros  + (size_t)(n0 + r) * NG + g0 + gb);
        s_lds[gb + 0][r] = s4.x; s_lds[gb + 1][r] = s4.y;
        s_lds[gb + 2][r] = s4.z; s_lds[gb + 3][r] = s4.w;
        z_lds[gb + 0][r] = z4.x; z_lds[gb + 1][r] = z4.y;
        z_lds[gb + 2][r] = z4.z; z_lds[gb + 3][r] = z4.w;
    }
    __syncthreads();

    const int nl = lane & 15;   // n within block (B-frag col)
    const int kq = lane >> 4;   // k-quad within k-step
    const int* pwp = pw + (size_t)(n0 + nl) * KP + kq * 4;
    const uint4* xfp = (const uint4*)xb;
    const int ks0 = kh * 128 + wave * KSW;   // global k-step base for this wave

    const int xm0 = nl;
    const int xkq = kq * 8;

    auto load_xfrag = [&](int mt, int ks) -> uint4 {
        if (USE_WS) {
            return xfp[(size_t)(mt * NKS + ks) * 64 + lane];
        } else {
            const float* src = x + (size_t)(xm0 + 16 * mt) * KK + ks * 32 + xkq;
            const float4 a = *(const float4*)(src);
            const float4 b = *(const float4*)(src + 4);
            return make_uint4(pack_bf16x2(a.x, a.y), pack_bf16x2(a.z, a.w),
                              pack_bf16x2(b.x, b.y), pack_bf16x2(b.z, b.w));
        }
    };

    floatx4 acc0 = {0.f, 0.f, 0.f, 0.f};
    floatx4 acc1 = {0.f, 0.f, 0.f, 0.f};

    int4  pwb[4];
    uint4 x0b[4], x1b[4];

#pragma unroll
    for (int i = 0; i < 3; ++i) {
        const int ks = ks0 + i;
        pwb[i] = *(const int4*)(pwp + ks * 16);
        x0b[i] = load_xfrag(0, ks);
        x1b[i] = load_xfrag(1, ks);
    }

#pragma unroll 4
    for (int i = 0; i < KSW; ++i) {
        const int slot = i & 3;
        if (i + 3 < KSW) {
            const int ks = ks0 + i + 3;
            const int ps = (i + 3) & 3;
            pwb[ps] = *(const int4*)(pwp + ks * 16);
            x0b[ps] = load_xfrag(0, ks);
            x1b[ps] = load_xfrag(1, ks);
        }
        const int gl  = (wave * KSW + i) >> 1;   // group local to this K-half
        const float sc = s_lds[gl][nl];
        const float zs = -z_lds[gl][nl] * sc;    // w = q*sc + zs

        union { uint4 v; short8 s; } bf;
        const int4 p = pwb[slot];
        bf.v.x = pack_bf16x2(fmaf((float)(p.x & 15), sc, zs),
                             fmaf((float)((p.x >> 4) & 15), sc, zs));
        bf.v.y = pack_bf16x2(fmaf((float)(p.y & 15), sc, zs),
                             fmaf((float)((p.y >> 4) & 15), sc, zs));
        bf.v.z = pack_bf16x2(fmaf((float)(p.z & 15), sc, zs),
                             fmaf((float)((p.z >> 4) & 15), sc, zs));
        bf.v.w = pack_bf16x2(fmaf((float)(p.w & 15), sc, zs),
                             fmaf((float)((p.w >> 4) & 15), sc, zs));

        union { uint4 v; short8 s; } a0, a1;
        a0.v = x0b[slot];
        a1.v = x1b[slot];
        acc0 = __builtin_amdgcn_mfma_f32_16x16x32_bf16(a0.s, bf.s, acc0, 0, 0, 0);
        acc1 = __builtin_amdgcn_mfma_f32_16x16x32_bf16(a1.s, bf.s, acc1, 0, 0, 0);
    }

    // cross-wave (K-split-within-block) reduction: C/D col=lane&15, row=(lane>>4)*4+r
#pragma unroll
    for (int r = 0; r < 4; ++r) {
        const int row = kq * 4 + r;
        red[wave][0][row * 16 + nl] = acc0[r];
        red[wave][1][row * 16 + nl] = acc1[r];
    }
    __syncthreads();

    // combine 4 waves, then atomically add the block's partial into out (bias pre-filled)
#pragma unroll
    for (int i = 0; i < 2; ++i) {
        const int e   = i * 256 + tid;     // 0..511 partial elems of this block
        const int mt  = e >> 8;
        const int idx = e & 255;
        const float s = red[0][mt][idx] + red[1][mt][idx] + red[2][mt][idx] + red[3][mt][idx];
        const int row = idx >> 4, col = idx & 15;
        atomicAdd(out + (size_t)(mt * 16 + row) * NN + n0 + col, s);
    }
}

extern "C" void kernel_launch(void* const* d_in, const int* in_sizes, int n_in,
                              void* d_out, int out_size, void* d_ws, size_t ws_size,
                              hipStream_t stream) {
    const float* x      = (const float*)d_in[0];
    const int*   pw     = (const int*)  d_in[1];
    const float* scales = (const float*)d_in[2];
    const float* zeros  = (const float*)d_in[3];
    const float* bias   = (const float*)d_in[4];
    float* out = (float*)d_out;

    const size_t need = (size_t)32768 * 16;   // 512 KB of bf16 A-frags
    const bool use_ws = (d_ws != nullptr && ws_size >= need);

    if (use_ws) {
        ushort* xb = (ushort*)d_ws;
        prep_kernel<<<128 + 256, 256, 0, stream>>>(x, bias, xb, out, 128);
        gptq_mfma_kernel<true><<<512 * KSPLIT, 256, 0, stream>>>(pw, scales, zeros, xb, x, out);
    } else {
        prep_kernel<<<256, 256, 0, stream>>>(x, bias, nullptr, out, 0);
        gptq_mfma_kernel<false><<<512 * KSPLIT, 256, 0, stream>>>(pw, scales, zeros,
                                                                  (const ushort*)nullptr, x, out);
    }
}

// Round 5
// 210.795 us; speedup vs baseline: 2.0800x; 1.0182x over previous
//
#include <hip/hip_runtime.h>
#include <hip/hip_bf16.h>
#include <stdint.h>

// GPTQ int4 linear via bf16 MFMA. M=32, K=8192, N=8192, group=64.
// R5: AITER-style async K-loop. All main-loop vmem = global_load_lds into
// per-wave triple-buffered LDS (6KB chunks: 2KB pw XOR-swizzled + 4KB x-frags),
// synced by manual s_waitcnt vmcnt(12/6/0) — no barriers, no register round-trip.
// Scales/zeros live in registers (16 groups per wave). Dequant uses v_perm RNE pack.

#define KK 8192
#define NN 8192
#define KP 4096      // int32 per weight row
#define NG 128       // quant groups per row
#define BN 16        // n per block
#define KSPLIT 2
#define KSW 32       // ksteps (32 k each) per wave
#define NKS 256      // total ksteps
#define NCH 16       // chunks per wave (2 ksteps each)
#define BUFB 6144    // bytes per ring buffer: pw 2048 + x 4096
#define WREG (3 * BUFB)

typedef __attribute__((ext_vector_type(8))) short short8;
typedef __attribute__((ext_vector_type(4))) float floatx4;
typedef const __attribute__((address_space(1))) void* gbl_t;
typedef __attribute__((address_space(3))) void* lds_t;

__device__ __forceinline__ void async16(const void* g, void* l) {
    __builtin_amdgcn_global_load_lds((gbl_t)(uintptr_t)g, (lds_t)(uintptr_t)l, 16, 0, 0);
}

__device__ __forceinline__ unsigned pack_bf16x2(float lo, float hi) {
    union { __hip_bfloat162 h; unsigned u; } c;
    c.h = __float22bfloat162_rn(make_float2(lo, hi));
    return c.u;
}

// dequant 2 nibbles -> packed bf16x2 (RNE, no NaN path needed: w is finite)
__device__ __forceinline__ unsigned dq2(int q, float sc, float zs) {
    float lo = fmaf((float)(q & 15),        sc, zs);
    float hi = fmaf((float)((q >> 4) & 15), sc, zs);
    unsigned ua = __float_as_uint(lo); ua += 0x7fffu + ((ua >> 16) & 1u);
    unsigned ub = __float_as_uint(hi); ub += 0x7fffu + ((ub >> 16) & 1u);
    return __builtin_amdgcn_perm(ub, ua, 0x07060302);   // [ub.hi16 : ua.hi16]
}

// blocks [0,xconv_blocks): x fp32 -> bf16 A-frags in xb; rest: out = bias.
__global__ void prep_kernel(const float* __restrict__ x, const float* __restrict__ bias,
                            ushort* __restrict__ xb, float* __restrict__ out,
                            int xconv_blocks)
{
    const int bx = blockIdx.x;
    if (bx < xconv_blocks) {
        const int tid = bx * 256 + threadIdx.x;   // 0..32767
        const int l   = tid & 63;
        const int ks  = (tid >> 6) & 255;
        const int mt  = tid >> 14;
        const int m   = (l & 15) + 16 * mt;
        const int kb  = ks * 32 + (l >> 4) * 8;
        const float* src = x + (size_t)m * KK + kb;
        const float4 a = *(const float4*)(src);
        const float4 b = *(const float4*)(src + 4);
        *(uint4*)(xb + (size_t)tid * 8) =
            make_uint4(pack_bf16x2(a.x, a.y), pack_bf16x2(a.z, a.w),
                       pack_bf16x2(b.x, b.y), pack_bf16x2(b.z, b.w));
    } else {
        const int f4 = (bx - xconv_blocks) * 256 + threadIdx.x;  // 0..65535
        const int n4 = f4 & (NN / 4 - 1);
        ((float4*)out)[f4] = ((const float4*)bias)[n4];
    }
}

__global__ __launch_bounds__(256, 2)
void gptq_mfma_lds(const int*   __restrict__ pw,
                   const float* __restrict__ scales,
                   const float* __restrict__ zeros,
                   const ushort* __restrict__ xb,
                   float* __restrict__ out)
{
    __shared__ uint4 smem4[4 * WREG / 16];    // 73728 B, 16B-aligned
    uint8_t* smem = (uint8_t*)smem4;

    const int tid  = threadIdx.x;
    const int lane = tid & 63;
    const int wave = tid >> 6;
    const int kh   = blockIdx.x & (KSPLIT - 1);
    const int n0   = (blockIdx.x >> 1) * BN;
    const int nl   = lane & 15;     // B-frag col (n_local)
    const int kq   = lane >> 4;     // k-quad
    const int ks0  = kh * 128 + wave * KSW;   // this wave's first global kstep
    const int g0   = ks0 >> 1;                // first quant group (16 per wave)

    // ---- scales/zeros -> registers: zsr = -z*s, one group per chunk ----
    float scr[16], zsr[16];
    {
        const float* sp = scales + (size_t)(n0 + nl) * NG + g0;
        const float* zp = zeros  + (size_t)(n0 + nl) * NG + g0;
#pragma unroll
        for (int i = 0; i < 4; ++i) {
            const float4 s4 = *(const float4*)(sp + i * 4);
            const float4 z4 = *(const float4*)(zp + i * 4);
            scr[i*4+0] = s4.x; zsr[i*4+0] = -z4.x * s4.x;
            scr[i*4+1] = s4.y; zsr[i*4+1] = -z4.y * s4.y;
            scr[i*4+2] = s4.z; zsr[i*4+2] = -z4.z * s4.z;
            scr[i*4+3] = s4.w; zsr[i*4+3] = -z4.w * s4.w;
        }
    }

    // ---- staging lane roles (pw XOR swizzle keeps readback conflict-free) ----
    const int srow = lane >> 3;          // row within 8-row instr block
    const int st   = lane & 7;           // LDS t-slot
    const int swz  = st ^ srow;          // global t within row's 128B chunk
    const int* pg0 = pw + (size_t)(n0 + 0 + srow) * KP + ks0 * 16 + swz * 4;
    const int* pg1 = pw + (size_t)(n0 + 8 + srow) * KP + ks0 * 16 + swz * 4;
    const uint4* xg0 = (const uint4*)xb + (size_t)(0 * NKS + ks0) * 64 + lane;
    const uint4* xg1 = (const uint4*)xb + (size_t)(1 * NKS + ks0) * 64 + lane;

    uint8_t* wbase = smem + wave * WREG;

#define STAGE(c) do {                                        \
        uint8_t* b_ = wbase + ((c) % 3) * BUFB;              \
        async16(pg0 + (c) * 32, b_);                         \
        async16(pg1 + (c) * 32, b_ + 1024);                  \
        async16(xg0 + (c) * 128,      b_ + 2048);            \
        async16(xg0 + (c) * 128 + 64, b_ + 3072);            \
        async16(xg1 + (c) * 128,      b_ + 4096);            \
        async16(xg1 + (c) * 128 + 64, b_ + 5120);            \
    } while (0)

    // pw readback offsets: row nl, slot t = (j*4+kq) ^ (nl&7)
    const int pwo0 = nl * 128 + (((0 * 4 + kq) ^ (nl & 7)) * 16);
    const int pwo1 = nl * 128 + (((1 * 4 + kq) ^ (nl & 7)) * 16);
    const int xo   = lane * 16;

    floatx4 acc0 = {0.f, 0.f, 0.f, 0.f};
    floatx4 acc1 = {0.f, 0.f, 0.f, 0.f};

    STAGE(0);
    STAGE(1);

#pragma unroll
    for (int c = 0; c < NCH; ++c) {
        if (c + 2 < NCH) {
            STAGE(c + 2);
            asm volatile("s_waitcnt vmcnt(12)" ::: "memory");
        } else if (c == NCH - 2) {
            asm volatile("s_waitcnt vmcnt(6)" ::: "memory");
        } else {
            asm volatile("s_waitcnt vmcnt(0)" ::: "memory");
        }
        uint8_t* b = wbase + (c % 3) * BUFB;
        const float sc = scr[c];
        const float zs = zsr[c];
#pragma unroll
        for (int j = 0; j < 2; ++j) {
            const int4  p  = *(const int4*) (b + (j ? pwo1 : pwo0));
            union { uint4 v; short8 s; } a0, a1, bf;
            a0.v = *(const uint4*)(b + 2048 + j * 1024 + xo);
            a1.v = *(const uint4*)(b + 4096 + j * 1024 + xo);
            bf.v.x = dq2(p.x, sc, zs);
            bf.v.y = dq2(p.y, sc, zs);
            bf.v.z = dq2(p.z, sc, zs);
            bf.v.w = dq2(p.w, sc, zs);
            acc0 = __builtin_amdgcn_mfma_f32_16x16x32_bf16(a0.s, bf.s, acc0, 0, 0, 0);
            acc1 = __builtin_amdgcn_mfma_f32_16x16x32_bf16(a1.s, bf.s, acc1, 0, 0, 0);
        }
    }
#undef STAGE

    // ---- epilogue: cross-wave reduce in LDS (overlaid on staging region) ----
    __syncthreads();
    float* red = (float*)smem;   // [wave][mt][256] = 8KB <= 72KB
#pragma unroll
    for (int r = 0; r < 4; ++r) {
        const int row = kq * 4 + r;
        red[(wave * 2 + 0) * 256 + row * 16 + nl] = acc0[r];
        red[(wave * 2 + 1) * 256 + row * 16 + nl] = acc1[r];
    }
    __syncthreads();

#pragma unroll
    for (int i = 0; i < 2; ++i) {
        const int e   = i * 256 + tid;
        const int mt  = e >> 8;
        const int idx = e & 255;
        const float s = red[(0 * 2 + mt) * 256 + idx] + red[(1 * 2 + mt) * 256 + idx]
                      + red[(2 * 2 + mt) * 256 + idx] + red[(3 * 2 + mt) * 256 + idx];
        atomicAdd(out + (size_t)(mt * 16 + (idx >> 4)) * NN + n0 + (idx & 15), s);
    }
}

// Fallback (no workspace): R4 register-path kernel, direct fp32 x loads.
__global__ __launch_bounds__(256, 4)
void gptq_mfma_fallback(const int*   __restrict__ pw,
                        const float* __restrict__ scales,
                        const float* __restrict__ zeros,
                        const float* __restrict__ x,
                        float* __restrict__ out)
{
    __shared__ float s_lds[64][BN + 1];
    __shared__ float z_lds[64][BN + 1];
    __shared__ float red[4][2][256];

    const int tid  = threadIdx.x;
    const int lane = tid & 63;
    const int wave = tid >> 6;
    const int kh   = blockIdx.x & (KSPLIT - 1);
    const int n0   = (blockIdx.x >> 1) * BN;
    const int g0   = kh * 64;

    {
        const int r  = tid >> 4;
        const int gb = (tid & 15) * 4;
        const float4 s4 = *(const float4*)(scales + (size_t)(n0 + r) * NG + g0 + gb);
        const float4 z4 = *(const float4*)(zeros  + (size_t)(n0 + r) * NG + g0 + gb);
        s_lds[gb + 0][r] = s4.x; s_lds[gb + 1][r] = s4.y;
        s_lds[gb + 2][r] = s4.z; s_lds[gb + 3][r] = s4.w;
        z_lds[gb + 0][r] = z4.x; z_lds[gb + 1][r] = z4.y;
        z_lds[gb + 2][r] = z4.z; z_lds[gb + 3][r] = z4.w;
    }
    __syncthreads();

    const int nl = lane & 15;
    const int kq = lane >> 4;
    const int* pwp = pw + (size_t)(n0 + nl) * KP + kq * 4;
    const int ks0 = kh * 128 + wave * KSW;

    auto load_xfrag = [&](int mt, int ks) -> uint4 {
        const float* src = x + (size_t)(nl + 16 * mt) * KK + ks * 32 + kq * 8;
        const float4 a = *(const float4*)(src);
        const float4 b = *(const float4*)(src + 4);
        return make_uint4(pack_bf16x2(a.x, a.y), pack_bf16x2(a.z, a.w),
                          pack_bf16x2(b.x, b.y), pack_bf16x2(b.z, b.w));
    };

    floatx4 acc0 = {0.f, 0.f, 0.f, 0.f};
    floatx4 acc1 = {0.f, 0.f, 0.f, 0.f};
    int4  pwb[4];
    uint4 x0b[4], x1b[4];

#pragma unroll
    for (int i = 0; i < 3; ++i) {
        const int ks = ks0 + i;
        pwb[i] = *(const int4*)(pwp + ks * 16);
        x0b[i] = load_xfrag(0, ks);
        x1b[i] = load_xfrag(1, ks);
    }

#pragma unroll 4
    for (int i = 0; i < KSW; ++i) {
        const int slot = i & 3;
        if (i + 3 < KSW) {
            const int ks = ks0 + i + 3;
            const int ps = (i + 3) & 3;
            pwb[ps] = *(const int4*)(pwp + ks * 16);
            x0b[ps] = load_xfrag(0, ks);
            x1b[ps] = load_xfrag(1, ks);
        }
        const int gl  = (wave * KSW + i) >> 1;
        const float sc = s_lds[gl][nl];
        const float zs = -z_lds[gl][nl] * sc;

        union { uint4 v; short8 s; } bf, a0, a1;
        const int4 p = pwb[slot];
        bf.v.x = dq2(p.x, sc, zs);
        bf.v.y = dq2(p.y, sc, zs);
        bf.v.z = dq2(p.z, sc, zs);
        bf.v.w = dq2(p.w, sc, zs);
        a0.v = x0b[slot];
        a1.v = x1b[slot];
        acc0 = __builtin_amdgcn_mfma_f32_16x16x32_bf16(a0.s, bf.s, acc0, 0, 0, 0);
        acc1 = __builtin_amdgcn_mfma_f32_16x16x32_bf16(a1.s, bf.s, acc1, 0, 0, 0);
    }

#pragma unroll
    for (int r = 0; r < 4; ++r) {
        const int row = kq * 4 + r;
        red[wave][0][row * 16 + nl] = acc0[r];
        red[wave][1][row * 16 + nl] = acc1[r];
    }
    __syncthreads();

#pragma unroll
    for (int i = 0; i < 2; ++i) {
        const int e   = i * 256 + tid;
        const int mt  = e >> 8;
        const int idx = e & 255;
        const float s = red[0][mt][idx] + red[1][mt][idx] + red[2][mt][idx] + red[3][mt][idx];
        atomicAdd(out + (size_t)(mt * 16 + (idx >> 4)) * NN + n0 + (idx & 15), s);
    }
}

extern "C" void kernel_launch(void* const* d_in, const int* in_sizes, int n_in,
                              void* d_out, int out_size, void* d_ws, size_t ws_size,
                              hipStream_t stream) {
    const float* x      = (const float*)d_in[0];
    const int*   pw     = (const int*)  d_in[1];
    const float* scales = (const float*)d_in[2];
    const float* zeros  = (const float*)d_in[3];
    const float* bias   = (const float*)d_in[4];
    float* out = (float*)d_out;

    const size_t need = (size_t)32768 * 16;   // 512 KB of bf16 A-frags
    if (d_ws != nullptr && ws_size >= need) {
        ushort* xb = (ushort*)d_ws;
        prep_kernel<<<128 + 256, 256, 0, stream>>>(x, bias, xb, out, 128);
        gptq_mfma_lds<<<512 * KSPLIT, 256, 0, stream>>>(pw, scales, zeros, xb, out);
    } else {
        prep_kernel<<<256, 256, 0, stream>>>(x, bias, nullptr, out, 0);
        gptq_mfma_fallback<<<512 * KSPLIT, 256, 0, stream>>>(pw, scales, zeros, x, out);
    }
}

// Round 6
// 209.928 us; speedup vs baseline: 2.0886x; 1.0041x over previous
//
#include <hip/hip_runtime.h>
#include <hip/hip_bf16.h>
#include <stdint.h>

// GPTQ int4 linear via bf16 MFMA. M=32, K=8192, N=8192, group=64.
// R6: DRAM-page-locality fix. pw staged via global_load_lds with 512 B
// contiguous runs per row (1 instr = 2 rows x 512 B), double-buffered 8 KB
// LDS superchunks (8 ksteps), vmcnt(8) sync, XOR swizzles (j^(row&7),
// q^(i&3)) for conflict-free readback with zero padding. KSPLIT=1: 512
// blocks, 2/CU, direct stores (no atomics). Scales/zeros in registers.

#define KK 8192
#define NN 8192
#define KP 4096      // int32 per weight row
#define NG 128       // quant groups per row
#define BN 16        // n per block
#define KSW 64       // ksteps (32 k) per wave: 4 waves * 64 * 32 = 8192
#define NKS 256      // total ksteps
#define SCK 8        // ksteps per superchunk
#define NSC 8        // superchunks per wave
#define PWBUF 8192   // bytes per superchunk pw buffer (16 rows x 512 B)
#define KSPLIT 2     // fallback only

typedef __attribute__((ext_vector_type(8))) short short8;
typedef __attribute__((ext_vector_type(4))) float floatx4;
typedef const __attribute__((address_space(1))) void* gbl_t;
typedef __attribute__((address_space(3))) void* lds_t;

__device__ __forceinline__ void async16(const void* g, void* l) {
    __builtin_amdgcn_global_load_lds((gbl_t)(uintptr_t)g, (lds_t)(uintptr_t)l, 16, 0, 0);
}

__device__ __forceinline__ unsigned pack_bf16x2(float lo, float hi) {
    union { __hip_bfloat162 h; unsigned u; } c;
    c.h = __float22bfloat162_rn(make_float2(lo, hi));
    return c.u;
}

// dequant 2 nibbles -> packed bf16x2 (RNE; w finite, no NaN path)
__device__ __forceinline__ unsigned dq2(int q, float sc, float zs) {
    float lo = fmaf((float)(q & 15),        sc, zs);
    float hi = fmaf((float)((q >> 4) & 15), sc, zs);
    unsigned ua = __float_as_uint(lo); ua += 0x7fffu + ((ua >> 16) & 1u);
    unsigned ub = __float_as_uint(hi); ub += 0x7fffu + ((ub >> 16) & 1u);
    return __builtin_amdgcn_perm(ub, ua, 0x07060302);   // [ub.hi16 : ua.hi16]
}

// blocks [0,xconv_blocks): x fp32 -> bf16 A-frags in xb; rest: out = bias.
__global__ void prep_kernel(const float* __restrict__ x, const float* __restrict__ bias,
                            ushort* __restrict__ xb, float* __restrict__ out,
                            int xconv_blocks)
{
    const int bx = blockIdx.x;
    if (bx < xconv_blocks) {
        const int tid = bx * 256 + threadIdx.x;   // 0..32767
        const int l   = tid & 63;
        const int ks  = (tid >> 6) & 255;
        const int mt  = tid >> 14;
        const int m   = (l & 15) + 16 * mt;
        const int kb  = ks * 32 + (l >> 4) * 8;
        const float* src = x + (size_t)m * KK + kb;
        const float4 a = *(const float4*)(src);
        const float4 b = *(const float4*)(src + 4);
        *(uint4*)(xb + (size_t)tid * 8) =
            make_uint4(pack_bf16x2(a.x, a.y), pack_bf16x2(a.z, a.w),
                       pack_bf16x2(b.x, b.y), pack_bf16x2(b.z, b.w));
    } else {
        const int f4 = (bx - xconv_blocks) * 256 + threadIdx.x;  // 0..65535
        const int n4 = f4 & (NN / 4 - 1);
        ((float4*)out)[f4] = ((const float4*)bias)[n4];
    }
}

__global__ __launch_bounds__(256, 2)
void gptq_mfma_main(const int*   __restrict__ pw,
                    const float* __restrict__ scales,
                    const float* __restrict__ zeros,
                    const float* __restrict__ bias,
                    const ushort* __restrict__ xb,
                    float* __restrict__ out)
{
    __shared__ uint4 smem4[65536 / 16];    // 4 waves x 2 x 8 KB pw buffers
    uint8_t* smem = (uint8_t*)smem4;

    const int tid  = threadIdx.x;
    const int lane = tid & 63;
    const int wave = tid >> 6;
    const int n0   = blockIdx.x * BN;
    const int nl   = lane & 15;     // B-frag col (n_local)
    const int kq   = lane >> 4;     // k-quad
    const int ks0  = wave * KSW;    // this wave's first kstep

    // ---- scales/zeros -> registers: 32 groups per wave ----
    float scr[32], zsr[32];
    {
        const float* sp = scales + (size_t)(n0 + nl) * NG + wave * 32;
        const float* zp = zeros  + (size_t)(n0 + nl) * NG + wave * 32;
#pragma unroll
        for (int i = 0; i < 8; ++i) {
            const float4 s4 = *(const float4*)(sp + i * 4);
            const float4 z4 = *(const float4*)(zp + i * 4);
            scr[i*4+0] = s4.x; zsr[i*4+0] = -z4.x * s4.x;
            scr[i*4+1] = s4.y; zsr[i*4+1] = -z4.y * s4.y;
            scr[i*4+2] = s4.z; zsr[i*4+2] = -z4.z * s4.z;
            scr[i*4+3] = s4.w; zsr[i*4+3] = -z4.w * s4.w;
        }
    }

    // ---- staging constants: instr i covers rows 2i,2i+1; 512 B contiguous/row ----
    // lane l: hw=l>>5 picks row parity; h=l&31: js=h>>2 (kstep slot), q=h&3 (16B grp)
    // global kstep in slot js is js^(row&7); dword-group stored at q is q^(i&3).
    const int hw = lane >> 5, h = lane & 31, js = h >> 2, q = h & 3;
    int bofs[8];
#pragma unroll
    for (int i = 0; i < 8; ++i) {
        const int r  = 2 * i + hw;
        const int jg = js ^ (r & 7);
        const int qg = q ^ (i & 3);
        bofs[i] = (n0 + r) * KP + jg * 16 + qg * 4;   // int32 units, + kb*16 later
    }
    uint8_t* wbuf = smem + wave * (2 * PWBUF);
    // readback base: row nl in instr i=nl>>1, half b=nl&1, dword-group kq^(i&3)
    const int pwo = (nl >> 1) * 1024 + (nl & 1) * 512 + ((kq ^ ((nl >> 1) & 3)) * 16);
    const int jx  = nl & 7;

#define STAGE(s) do {                                                  \
        uint8_t* b_ = wbuf + ((s) & 1) * PWBUF;                        \
        const int kb16_ = (ks0 + (s) * SCK) * 16;                      \
        _Pragma("unroll")                                              \
        for (int i_ = 0; i_ < 8; ++i_)                                 \
            async16(pw + bofs[i_] + kb16_, b_ + i_ * 1024);            \
    } while (0)

    const uint4* xfp = (const uint4*)xb;
    floatx4 acc0 = {0.f, 0.f, 0.f, 0.f};
    floatx4 acc1 = {0.f, 0.f, 0.f, 0.f};

    STAGE(0);

#pragma unroll
    for (int s = 0; s < NSC; ++s) {
        if (s + 1 < NSC) {
            STAGE(s + 1);
            // newest 8 outstanding = superchunk s+1's loads; all older drained.
            asm volatile("s_waitcnt vmcnt(8)" ::: "memory");
        } else {
            asm volatile("s_waitcnt vmcnt(0)" ::: "memory");
        }
        uint8_t* b = wbuf + (s & 1) * PWBUF;
#pragma unroll
        for (int j = 0; j < SCK; ++j) {
            const int ks = ks0 + s * SCK + j;
            const int4 p = *(const int4*)(b + pwo + ((j ^ jx) * 64));
            union { uint4 v; short8 sv; } a0, a1, bf;
            a0.v = xfp[(size_t)(0 * NKS + ks) * 64 + lane];
            a1.v = xfp[(size_t)(1 * NKS + ks) * 64 + lane];
            const float sc = scr[s * 4 + (j >> 1)];
            const float zs = zsr[s * 4 + (j >> 1)];
            bf.v.x = dq2(p.x, sc, zs);
            bf.v.y = dq2(p.y, sc, zs);
            bf.v.z = dq2(p.z, sc, zs);
            bf.v.w = dq2(p.w, sc, zs);
            acc0 = __builtin_amdgcn_mfma_f32_16x16x32_bf16(a0.sv, bf.sv, acc0, 0, 0, 0);
            acc1 = __builtin_amdgcn_mfma_f32_16x16x32_bf16(a1.sv, bf.sv, acc1, 0, 0, 0);
        }
    }
#undef STAGE

    // ---- epilogue: cross-wave reduce via LDS overlay, direct store + bias ----
    __syncthreads();
    float* red = (float*)smem;   // 8 KB overlay
#pragma unroll
    for (int r = 0; r < 4; ++r) {
        const int row = kq * 4 + r;
        red[(wave * 2 + 0) * 256 + row * 16 + nl] = acc0[r];
        red[(wave * 2 + 1) * 256 + row * 16 + nl] = acc1[r];
    }
    __syncthreads();

#pragma unroll
    for (int i = 0; i < 2; ++i) {
        const int e   = i * 256 + tid;
        const int mt  = e >> 8;
        const int idx = e & 255;
        const float sv = red[(0 * 2 + mt) * 256 + idx] + red[(1 * 2 + mt) * 256 + idx]
                       + red[(2 * 2 + mt) * 256 + idx] + red[(3 * 2 + mt) * 256 + idx];
        const int n = n0 + (idx & 15);
        out[(size_t)(mt * 16 + (idx >> 4)) * NN + n] = sv + bias[n];
    }
}

// Fallback (no workspace): register-path kernel, direct fp32 x loads, atomics.
__global__ __launch_bounds__(256, 4)
void gptq_mfma_fallback(const int*   __restrict__ pw,
                        const float* __restrict__ scales,
                        const float* __restrict__ zeros,
                        const float* __restrict__ x,
                        float* __restrict__ out)
{
    __shared__ float s_lds[64][BN + 1];
    __shared__ float z_lds[64][BN + 1];
    __shared__ float red[4][2][256];

    const int tid  = threadIdx.x;
    const int lane = tid & 63;
    const int wave = tid >> 6;
    const int kh   = blockIdx.x & (KSPLIT - 1);
    const int n0   = (blockIdx.x >> 1) * BN;
    const int g0   = kh * 64;

    {
        const int r  = tid >> 4;
        const int gb = (tid & 15) * 4;
        const float4 s4 = *(const float4*)(scales + (size_t)(n0 + r) * NG + g0 + gb);
        const float4 z4 = *(const float4*)(zeros  + (size_t)(n0 + r) * NG + g0 + gb);
        s_lds[gb + 0][r] = s4.x; s_lds[gb + 1][r] = s4.y;
        s_lds[gb + 2][r] = s4.z; s_lds[gb + 3][r] = s4.w;
        z_lds[gb + 0][r] = z4.x; z_lds[gb + 1][r] = z4.y;
        z_lds[gb + 2][r] = z4.z; z_lds[gb + 3][r] = z4.w;
    }
    __syncthreads();

    const int nl = lane & 15;
    const int kq = lane >> 4;
    const int* pwp = pw + (size_t)(n0 + nl) * KP + kq * 4;
    const int ks0 = kh * 128 + wave * 32;

    auto load_xfrag = [&](int mt, int ks) -> uint4 {
        const float* src = x + (size_t)(nl + 16 * mt) * KK + ks * 32 + kq * 8;
        const float4 a = *(const float4*)(src);
        const float4 b = *(const float4*)(src + 4);
        return make_uint4(pack_bf16x2(a.x, a.y), pack_bf16x2(a.z, a.w),
                          pack_bf16x2(b.x, b.y), pack_bf16x2(b.z, b.w));
    };

    floatx4 acc0 = {0.f, 0.f, 0.f, 0.f};
    floatx4 acc1 = {0.f, 0.f, 0.f, 0.f};
    int4  pwb[4];
    uint4 x0b[4], x1b[4];

#pragma unroll
    for (int i = 0; i < 3; ++i) {
        const int ks = ks0 + i;
        pwb[i] = *(const int4*)(pwp + ks * 16);
        x0b[i] = load_xfrag(0, ks);
        x1b[i] = load_xfrag(1, ks);
    }

#pragma unroll 4
    for (int i = 0; i < 32; ++i) {
        const int slot = i & 3;
        if (i + 3 < 32) {
            const int ks = ks0 + i + 3;
            const int ps = (i + 3) & 3;
            pwb[ps] = *(const int4*)(pwp + ks * 16);
            x0b[ps] = load_xfrag(0, ks);
            x1b[ps] = load_xfrag(1, ks);
        }
        const int gl  = (wave * 32 + i) >> 1;
        const float sc = s_lds[gl][nl];
        const float zs = -z_lds[gl][nl] * sc;

        union { uint4 v; short8 sv; } bf, a0, a1;
        const int4 p = pwb[slot];
        bf.v.x = dq2(p.x, sc, zs);
        bf.v.y = dq2(p.y, sc, zs);
        bf.v.z = dq2(p.z, sc, zs);
        bf.v.w = dq2(p.w, sc, zs);
        a0.v = x0b[slot];
        a1.v = x1b[slot];
        acc0 = __builtin_amdgcn_mfma_f32_16x16x32_bf16(a0.sv, bf.sv, acc0, 0, 0, 0);
        acc1 = __builtin_amdgcn_mfma_f32_16x16x32_bf16(a1.sv, bf.sv, acc1, 0, 0, 0);
    }

#pragma unroll
    for (int r = 0; r < 4; ++r) {
        const int row = kq * 4 + r;
        red[wave][0][row * 16 + nl] = acc0[r];
        red[wave][1][row * 16 + nl] = acc1[r];
    }
    __syncthreads();

#pragma unroll
    for (int i = 0; i < 2; ++i) {
        const int e   = i * 256 + tid;
        const int mt  = e >> 8;
        const int idx = e & 255;
        const float s = red[0][mt][idx] + red[1][mt][idx] + red[2][mt][idx] + red[3][mt][idx];
        atomicAdd(out + (size_t)(mt * 16 + (idx >> 4)) * NN + n0 + (idx & 15), s);
    }
}

extern "C" void kernel_launch(void* const* d_in, const int* in_sizes, int n_in,
                              void* d_out, int out_size, void* d_ws, size_t ws_size,
                              hipStream_t stream) {
    const float* x      = (const float*)d_in[0];
    const int*   pw     = (const int*)  d_in[1];
    const float* scales = (const float*)d_in[2];
    const float* zeros  = (const float*)d_in[3];
    const float* bias   = (const float*)d_in[4];
    float* out = (float*)d_out;

    const size_t need = (size_t)32768 * 16;   // 512 KB of bf16 A-frags
    if (d_ws != nullptr && ws_size >= need) {
        ushort* xb = (ushort*)d_ws;
        prep_kernel<<<128, 256, 0, stream>>>(x, bias, xb, out, 128);   // xconv only
        gptq_mfma_main<<<NN / BN, 256, 0, stream>>>(pw, scales, zeros, bias, xb, out);
    } else {
        prep_kernel<<<256, 256, 0, stream>>>(x, bias, nullptr, out, 0); // bias fill
        gptq_mfma_fallback<<<512 * KSPLIT, 256, 0, stream>>>(pw, scales, zeros, x, out);
    }
}